// Round 3
// baseline (11398.655 us; speedup 1.0000x reference)
//
#include <hip/hip_runtime.h>

// ---------------------------------------------------------------------------
// GCN forward, reassociated: per layer h = relu( (A_hat h) W + b ).
// Aggregate-first: the GEMM is row-local and runs IN-PLACE over the
// aggregation buffer. norm = dinv[r]*dinv[c]: dinv[r] applied in scatter,
// dinv[c] (+ self-loop dinv[c]^2 * h[c]) fused into the GEMM's A-staging.
// NOTE: harness delivers ALL integer inputs as int32 (not the reference's
// int64) — edge_index and batch are const int*.
// ---------------------------------------------------------------------------

constexpr int D = 128;
constexpr int NGRAPH = 512;
constexpr int SA_PITCH = 72;   // k-major A-tile pitch (floats), breaks 32-bank stride

__global__ __launch_bounds__(256) void zero_f4(float4* __restrict__ p, int n4) {
    int i = blockIdx.x * 256 + threadIdx.x;
    if (i < n4) p[i] = make_float4(0.f, 0.f, 0.f, 0.f);
}

// deg[c] += 1 per incoming edge (self-loop +1 added in make_dinv)
__global__ __launch_bounds__(256) void count_deg(const int* __restrict__ col,
                                                 int E, float* __restrict__ deg) {
    int e = blockIdx.x * 256 + threadIdx.x;
    if (e < E) atomicAdd(&deg[col[e]], 1.0f);
}

__global__ __launch_bounds__(256) void make_dinv(float* __restrict__ deg, int N) {
    int n = blockIdx.x * 256 + threadIdx.x;
    if (n < N) deg[n] = rsqrtf(deg[n] + 1.0f);
}

// P[c][:] += dinv[r] * H[r][:] for each edge r->c. 32 lanes/edge, float4/lane.
__global__ __launch_bounds__(256) void scatter_edges(const int* __restrict__ er,
                                                     const int* __restrict__ ec,
                                                     int E, const float* __restrict__ H,
                                                     const float* __restrict__ dinv,
                                                     float* __restrict__ P) {
    long long gid = (long long)blockIdx.x * 256 + threadIdx.x;
    int e = (int)(gid >> 5);
    if (e >= E) return;
    int lane = (int)(gid & 31);
    int r = er[e];
    int c = ec[e];
    float s = dinv[r];
    float4 v = ((const float4*)H)[(size_t)r * 32 + lane];
    float* dst = P + (size_t)c * 128 + lane * 4;
    atomicAdd(dst + 0, s * v.x);
    atomicAdd(dst + 1, s * v.y);
    atomicAdd(dst + 2, s * v.z);
    atomicAdd(dst + 3, s * v.w);
}

// In-place: P[n][:] = relu( (dinv[n]*(P[n][:] + dinv[n]*H[n][:])) @ W + bias ).
// Tile: 64 nodes x 128 cols per block; thread computes 4 nodes x 8 cols.
__global__ __launch_bounds__(256) void gemm_agg(float* __restrict__ P,
                                                const float* __restrict__ H,
                                                const float* __restrict__ W,
                                                const float* __restrict__ dinv,
                                                const float* __restrict__ bias, int N) {
    __shared__ __align__(16) float sW[32 * 128];       // 16 KB
    __shared__ __align__(16) float sA[32 * SA_PITCH];  // 9 KB, k-major

    const int tid = threadIdx.x;
    const int tx = tid & 15;   // cols 8*tx .. 8*tx+7
    const int ty = tid >> 4;   // nodes 4*ty .. 4*ty+3
    const int n0 = blockIdx.x * 64;

    float acc[4][8];
#pragma unroll
    for (int i = 0; i < 4; ++i)
#pragma unroll
        for (int j = 0; j < 8; ++j) acc[i][j] = 0.0f;

    const float4* P4 = (const float4*)P;
    const float4* H4 = (const float4*)H;
    const float4* W4 = (const float4*)W;

    for (int kc = 0; kc < 4; ++kc) {
        // stage W rows [kc*32, kc*32+32) x 128 : 1024 float4, 4/thread
#pragma unroll
        for (int i = 0; i < 4; ++i) {
            int f = tid + i * 256;
            int r = f >> 5, c4 = f & 31;
            ((float4*)sW)[r * 32 + c4] = W4[(kc * 32 + r) * 32 + c4];
        }
        // stage A rows (fused aggregation epilogue), transposed k-major: 512 float4
#pragma unroll
        for (int i = 0; i < 2; ++i) {
            int f = tid + i * 256;
            int n = f >> 3, c4 = f & 7;
            int node = n0 + n;
            float4 a = make_float4(0.f, 0.f, 0.f, 0.f);
            if (node < N) {
                float s = dinv[node];
                float4 p = P4[(size_t)node * 32 + kc * 8 + c4];
                float4 h = H4[(size_t)node * 32 + kc * 8 + c4];
                a.x = s * (p.x + s * h.x);
                a.y = s * (p.y + s * h.y);
                a.z = s * (p.z + s * h.z);
                a.w = s * (p.w + s * h.w);
            }
            int kl = c4 * 4;
            sA[(kl + 0) * SA_PITCH + n] = a.x;
            sA[(kl + 1) * SA_PITCH + n] = a.y;
            sA[(kl + 2) * SA_PITCH + n] = a.z;
            sA[(kl + 3) * SA_PITCH + n] = a.w;
        }
        __syncthreads();

#pragma unroll 8
        for (int k = 0; k < 32; ++k) {
            const float4 av = *(const float4*)(sA + k * SA_PITCH + 4 * ty);
            const float4 w0 = *(const float4*)(sW + k * 128 + 8 * tx);
            const float4 w1 = *(const float4*)(sW + k * 128 + 8 * tx + 4);
            const float a_[4] = {av.x, av.y, av.z, av.w};
            const float w_[8] = {w0.x, w0.y, w0.z, w0.w, w1.x, w1.y, w1.z, w1.w};
#pragma unroll
            for (int i = 0; i < 4; ++i)
#pragma unroll
                for (int j = 0; j < 8; ++j) acc[i][j] += a_[i] * w_[j];
        }
        __syncthreads();
    }

    // epilogue: + bias, relu, in-place store
    const float4 b0 = ((const float4*)bias)[2 * tx];
    const float4 b1 = ((const float4*)bias)[2 * tx + 1];
#pragma unroll
    for (int i = 0; i < 4; ++i) {
        int node = n0 + 4 * ty + i;
        if (node < N) {
            float4 o0, o1;
            o0.x = fmaxf(acc[i][0] + b0.x, 0.f);
            o0.y = fmaxf(acc[i][1] + b0.y, 0.f);
            o0.z = fmaxf(acc[i][2] + b0.z, 0.f);
            o0.w = fmaxf(acc[i][3] + b0.w, 0.f);
            o1.x = fmaxf(acc[i][4] + b1.x, 0.f);
            o1.y = fmaxf(acc[i][5] + b1.y, 0.f);
            o1.z = fmaxf(acc[i][6] + b1.z, 0.f);
            o1.w = fmaxf(acc[i][7] + b1.w, 0.f);
            ((float4*)P)[(size_t)node * 32 + 2 * tx] = o0;
            ((float4*)P)[(size_t)node * 32 + 2 * tx + 1] = o1;
        }
    }
}

// per-node dot h[n].Wl -> atomicAdd into graph sum; one wave (64 lanes) per node
__global__ __launch_bounds__(256) void node_dot(const float* __restrict__ H,
                                                const float* __restrict__ Wl,
                                                const int* __restrict__ batch, int N,
                                                float* __restrict__ gsum, int* __restrict__ gcnt) {
    long long gt = (long long)blockIdx.x * 256 + threadIdx.x;
    int n = (int)(gt >> 6);
    int lane = (int)(gt & 63);
    if (n >= N) return;
    float v = H[(size_t)n * 128 + lane] * Wl[lane] +
              H[(size_t)n * 128 + 64 + lane] * Wl[64 + lane];
#pragma unroll
    for (int off = 32; off > 0; off >>= 1) v += __shfl_down(v, off, 64);
    if (lane == 0) {
        int g = batch[n];
        atomicAdd(&gsum[g], v);
        atomicAdd(&gcnt[g], 1);
    }
}

__global__ __launch_bounds__(256) void finalize(const float* __restrict__ gsum,
                                                const int* __restrict__ gcnt,
                                                const float* __restrict__ bl,
                                                float* __restrict__ out) {
    int g = blockIdx.x * 256 + threadIdx.x;
    if (g < NGRAPH) {
        float c = (float)(gcnt[g] > 0 ? gcnt[g] : 1);
        out[g] = gsum[g] / c + bl[0];
    }
}

extern "C" void kernel_launch(void* const* d_in, const int* in_sizes, int n_in,
                              void* d_out, int out_size, void* d_ws, size_t ws_size,
                              hipStream_t stream) {
    const float* x       = (const float*)d_in[0];
    const int*   eidx    = (const int*)d_in[1];    // int32! harness converts int64 -> int32
    const int*   batch   = (const int*)d_in[2];    // int32!
    const float* Ws      = (const float*)d_in[3];
    const float* bs      = (const float*)d_in[4];
    const float* Wl      = (const float*)d_in[5];
    const float* bl      = (const float*)d_in[6];
    (void)n_in; (void)out_size;

    const int N = in_sizes[0] / D;
    const int E = in_sizes[1] / 2;
    const int* er = eidx;       // sources
    const int* ec = eidx + E;   // targets

    // ---- workspace carve (adaptive to ws_size) ----
    const size_t bufBytes = (size_t)N * D * sizeof(float);   // 51.2 MB
    const int Npad = (N + 63) & ~63;
    auto al = [](size_t v) { return (v + 255) & ~(size_t)255; };
    char* base = (char*)d_ws;

    float* wsA  = (float*)base;
    size_t off  = al(bufBytes);
    float* dinv = (float*)(base + off);            // Npad floats
    float* gsum = dinv + Npad;                     // NGRAPH floats
    int*   gcnt = (int*)(gsum + NGRAPH);           // NGRAPH ints
    size_t smallEnd = off + al((size_t)(Npad + 2 * NGRAPH) * sizeof(float));

    const bool twoBuf = ws_size >= smallEnd + bufBytes;
    float* wsB = twoBuf ? (float*)(base + smallEnd) : (float*)d_in[0];
    float* bufs[2] = { wsA, wsB };

    // ---- degree -> dinv; zero pool scratch ----
    const int smallN4 = (Npad + 2 * NGRAPH) / 4;
    zero_f4<<<(smallN4 + 255) / 256, 256, 0, stream>>>((float4*)dinv, smallN4);
    count_deg<<<(E + 255) / 256, 256, 0, stream>>>(ec, E, dinv);
    make_dinv<<<(N + 255) / 256, 256, 0, stream>>>(dinv, N);

    // ---- 4 layers: zero P -> scatter -> in-place GEMM(+agg epilogue,+bias,+relu) ----
    const int n4 = N * D / 4;
    for (int i = 0; i < 4; ++i) {
        float* P = bufs[i & 1];
        const float* H = (i == 0) ? x : bufs[(i - 1) & 1];
        zero_f4<<<(n4 + 255) / 256, 256, 0, stream>>>((float4*)P, n4);
        long long tot = (long long)E * 32;
        scatter_edges<<<(int)((tot + 255) / 256), 256, 0, stream>>>(er, ec, E, H, dinv, P);
        gemm_agg<<<(N + 63) / 64, 256, 0, stream>>>(P, H, Ws + (size_t)i * D * D, dinv,
                                                    bs + (size_t)i * D, N);
    }

    // ---- mean pool + linear head (final features in bufs[1]) ----
    long long tot = (long long)N * 64;
    node_dot<<<(int)((tot + 255) / 256), 256, 0, stream>>>(bufs[1], Wl, batch, N, gsum, gcnt);
    finalize<<<2, 256, 0, stream>>>(gsum, gcnt, bl, (float*)d_out);
}

// Round 4
// 1165.056 us; speedup vs baseline: 9.7838x; 9.7838x over previous
//
#include <hip/hip_runtime.h>

// ---------------------------------------------------------------------------
// GCN forward, reassociated: per layer h = relu( (A_hat h) W + b ).
// Aggregation is PULL-side over an on-device-built CSR (sorted by target):
// zero atomics in the hot path (R3 showed 819M f32 atomics -> 3.2GB fabric
// writes per layer = 94% of runtime). CSR built once, reused by all 4 layers.
// norm = dinv[r]*dinv[c]: dinv[r] folded into CSR edge vals, dinv[c] (+
// self-loop dinv[c]^2 * h[c]) fused into the GEMM's A-staging.
// NOTE: harness delivers ALL integer inputs as int32 — edge_index/batch are
// const int*.
// ---------------------------------------------------------------------------

constexpr int D = 128;
constexpr int NGRAPH = 512;
constexpr int SA_PITCH = 72;   // k-major A-tile pitch (floats), breaks 32-bank stride

__global__ __launch_bounds__(256) void zero_i4(int4* __restrict__ p, int n4) {
    int i = blockIdx.x * 256 + threadIdx.x;
    if (i < n4) p[i] = make_int4(0, 0, 0, 0);
}

// degi[c] += 1 per incoming edge (self-loop +1 added in make_dinv)
__global__ __launch_bounds__(256) void count_deg(const int* __restrict__ col,
                                                 int E, int* __restrict__ degi) {
    int e = blockIdx.x * 256 + threadIdx.x;
    if (e < E) atomicAdd(&degi[col[e]], 1);
}

__global__ __launch_bounds__(256) void make_dinv(const int* __restrict__ degi,
                                                 float* __restrict__ dinv, int N) {
    int n = blockIdx.x * 256 + threadIdx.x;
    if (n < N) dinv[n] = rsqrtf((float)degi[n] + 1.0f);
}

// ---- 3-phase exclusive prefix sum over degi[N] -> rowptr[N+1] --------------
// 1024 elements per block (256 threads x 4). N=100k -> 98 blocks (<256, so the
// single-block phase-2 scan with 256 threads covers all block sums).
__global__ __launch_bounds__(256) void scan1(const int* __restrict__ deg, int N,
                                             int* __restrict__ bsum) {
    __shared__ int s[256];
    int t = threadIdx.x, base = blockIdx.x * 1024 + t * 4;
    int v = 0;
#pragma unroll
    for (int i = 0; i < 4; ++i) { int idx = base + i; if (idx < N) v += deg[idx]; }
    s[t] = v; __syncthreads();
    for (int off = 128; off > 0; off >>= 1) {
        if (t < off) s[t] += s[t + off];
        __syncthreads();
    }
    if (t == 0) bsum[blockIdx.x] = s[0];
}

__global__ __launch_bounds__(256) void scan2(int* __restrict__ bsum, int NB) {
    __shared__ int s[256];
    int t = threadIdx.x;
    int v = (t < NB) ? bsum[t] : 0;
    s[t] = v; __syncthreads();
    for (int off = 1; off < 256; off <<= 1) {
        int x = (t >= off) ? s[t - off] : 0;
        __syncthreads();
        s[t] += x;
        __syncthreads();
    }
    if (t < NB) bsum[t] = s[t] - v;   // exclusive
}

__global__ __launch_bounds__(256) void scan3(const int* __restrict__ deg,
                                             const int* __restrict__ bsumEx,
                                             int N, int E, int* __restrict__ rowptr) {
    __shared__ int s[256];
    int t = threadIdx.x, base = blockIdx.x * 1024 + t * 4;
    int v[4], sum = 0;
#pragma unroll
    for (int i = 0; i < 4; ++i) { int idx = base + i; v[i] = (idx < N) ? deg[idx] : 0; sum += v[i]; }
    s[t] = sum; __syncthreads();
    for (int off = 1; off < 256; off <<= 1) {
        int x = (t >= off) ? s[t - off] : 0;
        __syncthreads();
        s[t] += x;
        __syncthreads();
    }
    int run = bsumEx[blockIdx.x] + s[t] - sum;   // exclusive within grid
#pragma unroll
    for (int i = 0; i < 4; ++i) {
        int idx = base + i;
        if (idx < N) rowptr[idx] = run;
        run += v[i];
    }
    if (blockIdx.x == 0 && t == 0) rowptr[N] = E;
}

// slot-fill: srcs/vals sorted by target node (order within a node arbitrary)
__global__ __launch_bounds__(256) void fill_edges(const int* __restrict__ er,
                                                  const int* __restrict__ ec, int E,
                                                  const int* __restrict__ rowptr,
                                                  int* __restrict__ cursor,
                                                  const float* __restrict__ dinv,
                                                  int* __restrict__ srcs,
                                                  float* __restrict__ vals) {
    int e = blockIdx.x * 256 + threadIdx.x;
    if (e >= E) return;
    int r = er[e], c = ec[e];
    int pos = rowptr[c] + atomicAdd(&cursor[c], 1);
    srcs[pos] = r;
    vals[pos] = dinv[r];
}

// P[n][:] = sum_{j in CSR row n} vals[j] * H[srcs[j]][:]   — no atomics.
// Half-wave (32 lanes x float4) per node, 8 nodes per 256-block.
__global__ __launch_bounds__(256) void pull_agg(const int* __restrict__ rowptr,
                                                const int* __restrict__ srcs,
                                                const float* __restrict__ vals,
                                                const float* __restrict__ H,
                                                float* __restrict__ P, int N) {
    int node = blockIdx.x * 8 + (threadIdx.x >> 5);
    int lane = threadIdx.x & 31;
    if (node >= N) return;
    int j = rowptr[node], end = rowptr[node + 1];
    const float4* H4 = (const float4*)H;
    float4 acc = make_float4(0.f, 0.f, 0.f, 0.f);
    for (; j + 1 < end; j += 2) {
        int r0 = srcs[j], r1 = srcs[j + 1];
        float s0 = vals[j], s1 = vals[j + 1];
        float4 a = H4[(size_t)r0 * 32 + lane];
        float4 b = H4[(size_t)r1 * 32 + lane];
        acc.x += s0 * a.x + s1 * b.x;
        acc.y += s0 * a.y + s1 * b.y;
        acc.z += s0 * a.z + s1 * b.z;
        acc.w += s0 * a.w + s1 * b.w;
    }
    if (j < end) {
        int r0 = srcs[j];
        float s0 = vals[j];
        float4 a = H4[(size_t)r0 * 32 + lane];
        acc.x += s0 * a.x; acc.y += s0 * a.y; acc.z += s0 * a.z; acc.w += s0 * a.w;
    }
    ((float4*)P)[(size_t)node * 32 + lane] = acc;
}

// In-place: P[n][:] = relu( (dinv[n]*(P[n][:] + dinv[n]*H[n][:])) @ W + bias ).
__global__ __launch_bounds__(256) void gemm_agg(float* __restrict__ P,
                                                const float* __restrict__ H,
                                                const float* __restrict__ W,
                                                const float* __restrict__ dinv,
                                                const float* __restrict__ bias, int N) {
    __shared__ __align__(16) float sW[32 * 128];
    __shared__ __align__(16) float sA[32 * SA_PITCH];

    const int tid = threadIdx.x;
    const int tx = tid & 15;
    const int ty = tid >> 4;
    const int n0 = blockIdx.x * 64;

    float acc[4][8];
#pragma unroll
    for (int i = 0; i < 4; ++i)
#pragma unroll
        for (int j = 0; j < 8; ++j) acc[i][j] = 0.0f;

    const float4* P4 = (const float4*)P;
    const float4* H4 = (const float4*)H;
    const float4* W4 = (const float4*)W;

    for (int kc = 0; kc < 4; ++kc) {
#pragma unroll
        for (int i = 0; i < 4; ++i) {
            int f = tid + i * 256;
            int r = f >> 5, c4 = f & 31;
            ((float4*)sW)[r * 32 + c4] = W4[(kc * 32 + r) * 32 + c4];
        }
#pragma unroll
        for (int i = 0; i < 2; ++i) {
            int f = tid + i * 256;
            int n = f >> 3, c4 = f & 7;
            int node = n0 + n;
            float4 a = make_float4(0.f, 0.f, 0.f, 0.f);
            if (node < N) {
                float s = dinv[node];
                float4 p = P4[(size_t)node * 32 + kc * 8 + c4];
                float4 h = H4[(size_t)node * 32 + kc * 8 + c4];
                a.x = s * (p.x + s * h.x);
                a.y = s * (p.y + s * h.y);
                a.z = s * (p.z + s * h.z);
                a.w = s * (p.w + s * h.w);
            }
            int kl = c4 * 4;
            sA[(kl + 0) * SA_PITCH + n] = a.x;
            sA[(kl + 1) * SA_PITCH + n] = a.y;
            sA[(kl + 2) * SA_PITCH + n] = a.z;
            sA[(kl + 3) * SA_PITCH + n] = a.w;
        }
        __syncthreads();

#pragma unroll 8
        for (int k = 0; k < 32; ++k) {
            const float4 av = *(const float4*)(sA + k * SA_PITCH + 4 * ty);
            const float4 w0 = *(const float4*)(sW + k * 128 + 8 * tx);
            const float4 w1 = *(const float4*)(sW + k * 128 + 8 * tx + 4);
            const float a_[4] = {av.x, av.y, av.z, av.w};
            const float w_[8] = {w0.x, w0.y, w0.z, w0.w, w1.x, w1.y, w1.z, w1.w};
#pragma unroll
            for (int i = 0; i < 4; ++i)
#pragma unroll
                for (int j = 0; j < 8; ++j) acc[i][j] += a_[i] * w_[j];
        }
        __syncthreads();
    }

    const float4 b0 = ((const float4*)bias)[2 * tx];
    const float4 b1 = ((const float4*)bias)[2 * tx + 1];
#pragma unroll
    for (int i = 0; i < 4; ++i) {
        int node = n0 + 4 * ty + i;
        if (node < N) {
            float4 o0, o1;
            o0.x = fmaxf(acc[i][0] + b0.x, 0.f);
            o0.y = fmaxf(acc[i][1] + b0.y, 0.f);
            o0.z = fmaxf(acc[i][2] + b0.z, 0.f);
            o0.w = fmaxf(acc[i][3] + b0.w, 0.f);
            o1.x = fmaxf(acc[i][4] + b1.x, 0.f);
            o1.y = fmaxf(acc[i][5] + b1.y, 0.f);
            o1.z = fmaxf(acc[i][6] + b1.z, 0.f);
            o1.w = fmaxf(acc[i][7] + b1.w, 0.f);
            ((float4*)P)[(size_t)node * 32 + 2 * tx] = o0;
            ((float4*)P)[(size_t)node * 32 + 2 * tx + 1] = o1;
        }
    }
}

// per-node dot h[n].Wl -> atomicAdd into graph sum; one wave (64 lanes) per node
__global__ __launch_bounds__(256) void node_dot(const float* __restrict__ H,
                                                const float* __restrict__ Wl,
                                                const int* __restrict__ batch, int N,
                                                float* __restrict__ gsum, int* __restrict__ gcnt) {
    long long gt = (long long)blockIdx.x * 256 + threadIdx.x;
    int n = (int)(gt >> 6);
    int lane = (int)(gt & 63);
    if (n >= N) return;
    float v = H[(size_t)n * 128 + lane] * Wl[lane] +
              H[(size_t)n * 128 + 64 + lane] * Wl[64 + lane];
#pragma unroll
    for (int off = 32; off > 0; off >>= 1) v += __shfl_down(v, off, 64);
    if (lane == 0) {
        int g = batch[n];
        atomicAdd(&gsum[g], v);
        atomicAdd(&gcnt[g], 1);
    }
}

__global__ __launch_bounds__(256) void finalize(const float* __restrict__ gsum,
                                                const int* __restrict__ gcnt,
                                                const float* __restrict__ bl,
                                                float* __restrict__ out) {
    int g = blockIdx.x * 256 + threadIdx.x;
    if (g < NGRAPH) {
        float c = (float)(gcnt[g] > 0 ? gcnt[g] : 1);
        out[g] = gsum[g] / c + bl[0];
    }
}

extern "C" void kernel_launch(void* const* d_in, const int* in_sizes, int n_in,
                              void* d_out, int out_size, void* d_ws, size_t ws_size,
                              hipStream_t stream) {
    const float* x     = (const float*)d_in[0];
    const int*   eidx  = (const int*)d_in[1];    // int32 (harness converts int64)
    const int*   batch = (const int*)d_in[2];
    const float* Ws    = (const float*)d_in[3];
    const float* bs    = (const float*)d_in[4];
    const float* Wl    = (const float*)d_in[5];
    const float* bl    = (const float*)d_in[6];
    (void)n_in; (void)out_size;

    const int N = in_sizes[0] / D;
    const int E = in_sizes[1] / 2;
    const int* er = eidx;       // sources
    const int* ec = eidx + E;   // targets

    // ---- workspace carve ----
    const size_t bufBytes = (size_t)N * D * sizeof(float);   // 51.2 MB
    const int Npad = (N + 63) & ~63;
    auto al = [](size_t v) { return (v + 255) & ~(size_t)255; };
    char* base = (char*)d_ws;
    size_t off = 0;

    float* wsA = (float*)base;               off = al(bufBytes);
    // zero-block: degi, cursor, gsum, gcnt (contiguous -> one zero kernel)
    int*   degi   = (int*)(base + off);
    int*   cursor = degi + Npad;
    float* gsum   = (float*)(cursor + Npad);
    int*   gcnt   = (int*)(gsum + NGRAPH);
    const int zeroInts = 2 * Npad + 2 * NGRAPH;
    off = al(off + (size_t)zeroInts * sizeof(int));
    float* dinv   = (float*)(base + off);    off = al(off + (size_t)Npad * sizeof(float));
    int*   rowptr = (int*)(base + off);      off = al(off + (size_t)(Npad + 64) * sizeof(int));
    int*   bsum   = (int*)(base + off);      off = al(off + 256 * sizeof(int));
    int*   srcs   = (int*)(base + off);      off = al(off + (size_t)E * sizeof(int));
    float* vals   = (float*)(base + off);    off = al(off + (size_t)E * sizeof(float));

    const bool twoBuf = ws_size >= off + bufBytes;
    float* wsB = twoBuf ? (float*)(base + off) : (float*)d_in[0];
    float* bufs[2] = { wsA, wsB };

    // ---- CSR build (once; reused by all 4 layers) ----
    zero_i4<<<(zeroInts / 4 + 255) / 256, 256, 0, stream>>>((int4*)degi, zeroInts / 4);
    count_deg<<<(E + 255) / 256, 256, 0, stream>>>(ec, E, degi);
    make_dinv<<<(N + 255) / 256, 256, 0, stream>>>(degi, dinv, N);
    const int NB = (N + 1023) / 1024;        // 98 (< 256: scan2 single-block ok)
    scan1<<<NB, 256, 0, stream>>>(degi, N, bsum);
    scan2<<<1, 256, 0, stream>>>(bsum, NB);
    scan3<<<NB, 256, 0, stream>>>(degi, bsum, N, E, rowptr);
    fill_edges<<<(E + 255) / 256, 256, 0, stream>>>(er, ec, E, rowptr, cursor, dinv, srcs, vals);

    // ---- 4 layers: pull-aggregate (no atomics) -> in-place GEMM ----
    for (int i = 0; i < 4; ++i) {
        float* P = bufs[i & 1];
        const float* H = (i == 0) ? x : bufs[(i - 1) & 1];
        pull_agg<<<(N + 7) / 8, 256, 0, stream>>>(rowptr, srcs, vals, H, P, N);
        gemm_agg<<<(N + 63) / 64, 256, 0, stream>>>(P, H, Ws + (size_t)i * D * D, dinv,
                                                    bs + (size_t)i * D, N);
    }

    // ---- mean pool + linear head (final features in bufs[1]) ----
    long long tot = (long long)N * 64;
    node_dot<<<(int)((tot + 255) / 256), 256, 0, stream>>>(bufs[1], Wl, batch, N, gsum, gcnt);
    finalize<<<2, 256, 0, stream>>>(gsum, gcnt, bl, (float*)d_out);
}

// Round 5
// 996.501 us; speedup vs baseline: 11.4387x; 1.1691x over previous
//
#include <hip/hip_runtime.h>

// ---------------------------------------------------------------------------
// GCN forward, reassociated: per layer h = relu( (A_hat h) W + b ).
// Pull-side aggregation over on-device CSR (built once, reused 4x): zero
// atomics in all hot paths. R4 lesson: sorted `batch` made the 200k pooling
// atomics serialize on 512 addresses (245us!) -> pooling is now two-stage
// and atomic-free (dots scratch + per-graph binary-searched block reduce).
// pull_agg folds the full normalization: P[n] = dinv[n]*(sum vals*H[src]
// + dinv[n]*H[n]), so gemm_agg reads only P.
// NOTE: harness delivers integer inputs as int32 (edge_index/batch: int*).
// ---------------------------------------------------------------------------

constexpr int D = 128;
constexpr int NGRAPH = 512;
constexpr int SA_PITCH = 72;   // k-major A-tile pitch (floats), breaks 32-bank stride

__global__ __launch_bounds__(256) void zero_i4(int4* __restrict__ p, int n4) {
    int i = blockIdx.x * 256 + threadIdx.x;
    if (i < n4) p[i] = make_int4(0, 0, 0, 0);
}

// degi[c] += 1 per incoming edge (self-loop +1 added in make_dinv)
__global__ __launch_bounds__(256) void count_deg(const int* __restrict__ col,
                                                 int E, int* __restrict__ degi) {
    int e = blockIdx.x * 256 + threadIdx.x;
    if (e < E) atomicAdd(&degi[col[e]], 1);
}

__global__ __launch_bounds__(256) void make_dinv(const int* __restrict__ degi,
                                                 float* __restrict__ dinv, int N) {
    int n = blockIdx.x * 256 + threadIdx.x;
    if (n < N) dinv[n] = rsqrtf((float)degi[n] + 1.0f);
}

// ---- 3-phase exclusive prefix sum over degi[N] -> rowptr[N+1] --------------
__global__ __launch_bounds__(256) void scan1(const int* __restrict__ deg, int N,
                                             int* __restrict__ bsum) {
    __shared__ int s[256];
    int t = threadIdx.x, base = blockIdx.x * 1024 + t * 4;
    int v = 0;
#pragma unroll
    for (int i = 0; i < 4; ++i) { int idx = base + i; if (idx < N) v += deg[idx]; }
    s[t] = v; __syncthreads();
    for (int off = 128; off > 0; off >>= 1) {
        if (t < off) s[t] += s[t + off];
        __syncthreads();
    }
    if (t == 0) bsum[blockIdx.x] = s[0];
}

__global__ __launch_bounds__(256) void scan2(int* __restrict__ bsum, int NB) {
    __shared__ int s[256];
    int t = threadIdx.x;
    int v = (t < NB) ? bsum[t] : 0;
    s[t] = v; __syncthreads();
    for (int off = 1; off < 256; off <<= 1) {
        int x = (t >= off) ? s[t - off] : 0;
        __syncthreads();
        s[t] += x;
        __syncthreads();
    }
    if (t < NB) bsum[t] = s[t] - v;   // exclusive
}

__global__ __launch_bounds__(256) void scan3(const int* __restrict__ deg,
                                             const int* __restrict__ bsumEx,
                                             int N, int E, int* __restrict__ rowptr) {
    __shared__ int s[256];
    int t = threadIdx.x, base = blockIdx.x * 1024 + t * 4;
    int v[4], sum = 0;
#pragma unroll
    for (int i = 0; i < 4; ++i) { int idx = base + i; v[i] = (idx < N) ? deg[idx] : 0; sum += v[i]; }
    s[t] = sum; __syncthreads();
    for (int off = 1; off < 256; off <<= 1) {
        int x = (t >= off) ? s[t - off] : 0;
        __syncthreads();
        s[t] += x;
        __syncthreads();
    }
    int run = bsumEx[blockIdx.x] + s[t] - sum;
#pragma unroll
    for (int i = 0; i < 4; ++i) {
        int idx = base + i;
        if (idx < N) rowptr[idx] = run;
        run += v[i];
    }
    if (blockIdx.x == 0 && t == 0) rowptr[N] = E;
}

// slot-fill: srcs/vals grouped by target node (order within a node arbitrary)
__global__ __launch_bounds__(256) void fill_edges(const int* __restrict__ er,
                                                  const int* __restrict__ ec, int E,
                                                  const int* __restrict__ rowptr,
                                                  int* __restrict__ cursor,
                                                  const float* __restrict__ dinv,
                                                  int* __restrict__ srcs,
                                                  float* __restrict__ vals) {
    int e = blockIdx.x * 256 + threadIdx.x;
    if (e >= E) return;
    int r = er[e], c = ec[e];
    int pos = rowptr[c] + atomicAdd(&cursor[c], 1);
    srcs[pos] = r;
    vals[pos] = dinv[r];
}

// P[n][:] = dinv[n] * ( sum_j vals[j]*H[srcs[j]][:] + dinv[n]*H[n][:] )
// Half-wave (32 lanes x float4) per node; 4-edge unroll for MLP. No atomics.
__global__ __launch_bounds__(256) void pull_agg(const int* __restrict__ rowptr,
                                                const int* __restrict__ srcs,
                                                const float* __restrict__ vals,
                                                const float* __restrict__ dinv,
                                                const float* __restrict__ H,
                                                float* __restrict__ P, int N) {
    int node = blockIdx.x * 8 + (threadIdx.x >> 5);
    int lane = threadIdx.x & 31;
    if (node >= N) return;
    int j = rowptr[node], end = rowptr[node + 1];
    const float4* H4 = (const float4*)H;
    float sn = dinv[node];
    // self-loop term: dinv[n]*H[n] (whole acc scaled by dinv[n] at the end)
    float4 hs = H4[(size_t)node * 32 + lane];
    float4 acc = make_float4(sn * hs.x, sn * hs.y, sn * hs.z, sn * hs.w);
    for (; j + 3 < end; j += 4) {
        int r0 = srcs[j], r1 = srcs[j + 1], r2 = srcs[j + 2], r3 = srcs[j + 3];
        float s0 = vals[j], s1 = vals[j + 1], s2 = vals[j + 2], s3 = vals[j + 3];
        float4 a = H4[(size_t)r0 * 32 + lane];
        float4 b = H4[(size_t)r1 * 32 + lane];
        float4 c = H4[(size_t)r2 * 32 + lane];
        float4 d = H4[(size_t)r3 * 32 + lane];
        acc.x += s0 * a.x + s1 * b.x + s2 * c.x + s3 * d.x;
        acc.y += s0 * a.y + s1 * b.y + s2 * c.y + s3 * d.y;
        acc.z += s0 * a.z + s1 * b.z + s2 * c.z + s3 * d.z;
        acc.w += s0 * a.w + s1 * b.w + s2 * c.w + s3 * d.w;
    }
    for (; j < end; ++j) {
        int r0 = srcs[j];
        float s0 = vals[j];
        float4 a = H4[(size_t)r0 * 32 + lane];
        acc.x += s0 * a.x; acc.y += s0 * a.y; acc.z += s0 * a.z; acc.w += s0 * a.w;
    }
    acc.x *= sn; acc.y *= sn; acc.z *= sn; acc.w *= sn;
    ((float4*)P)[(size_t)node * 32 + lane] = acc;
}

// In-place: P[n][:] = relu( P[n][:] @ W + bias ).  64 nodes x 128 cols/block.
__global__ __launch_bounds__(256) void gemm_agg(float* __restrict__ P,
                                                const float* __restrict__ W,
                                                const float* __restrict__ bias, int N) {
    __shared__ __align__(16) float sW[32 * 128];
    __shared__ __align__(16) float sA[32 * SA_PITCH];

    const int tid = threadIdx.x;
    const int tx = tid & 15;
    const int ty = tid >> 4;
    const int n0 = blockIdx.x * 64;

    float acc[4][8];
#pragma unroll
    for (int i = 0; i < 4; ++i)
#pragma unroll
        for (int j = 0; j < 8; ++j) acc[i][j] = 0.0f;

    const float4* P4 = (const float4*)P;
    const float4* W4 = (const float4*)W;

    for (int kc = 0; kc < 4; ++kc) {
#pragma unroll
        for (int i = 0; i < 4; ++i) {
            int f = tid + i * 256;
            int r = f >> 5, c4 = f & 31;
            ((float4*)sW)[r * 32 + c4] = W4[(kc * 32 + r) * 32 + c4];
        }
#pragma unroll
        for (int i = 0; i < 2; ++i) {
            int f = tid + i * 256;
            int n = f >> 3, c4 = f & 7;
            int node = n0 + n;
            float4 a = (node < N) ? P4[(size_t)node * 32 + kc * 8 + c4]
                                  : make_float4(0.f, 0.f, 0.f, 0.f);
            int kl = c4 * 4;
            sA[(kl + 0) * SA_PITCH + n] = a.x;
            sA[(kl + 1) * SA_PITCH + n] = a.y;
            sA[(kl + 2) * SA_PITCH + n] = a.z;
            sA[(kl + 3) * SA_PITCH + n] = a.w;
        }
        __syncthreads();

#pragma unroll 8
        for (int k = 0; k < 32; ++k) {
            const float4 av = *(const float4*)(sA + k * SA_PITCH + 4 * ty);
            const float4 w0 = *(const float4*)(sW + k * 128 + 8 * tx);
            const float4 w1 = *(const float4*)(sW + k * 128 + 8 * tx + 4);
            const float a_[4] = {av.x, av.y, av.z, av.w};
            const float w_[8] = {w0.x, w0.y, w0.z, w0.w, w1.x, w1.y, w1.z, w1.w};
#pragma unroll
            for (int i = 0; i < 4; ++i)
#pragma unroll
                for (int j = 0; j < 8; ++j) acc[i][j] += a_[i] * w_[j];
        }
        __syncthreads();
    }

    const float4 b0 = ((const float4*)bias)[2 * tx];
    const float4 b1 = ((const float4*)bias)[2 * tx + 1];
#pragma unroll
    for (int i = 0; i < 4; ++i) {
        int node = n0 + 4 * ty + i;
        if (node < N) {
            float4 o0, o1;
            o0.x = fmaxf(acc[i][0] + b0.x, 0.f);
            o0.y = fmaxf(acc[i][1] + b0.y, 0.f);
            o0.z = fmaxf(acc[i][2] + b0.z, 0.f);
            o0.w = fmaxf(acc[i][3] + b0.w, 0.f);
            o1.x = fmaxf(acc[i][4] + b1.x, 0.f);
            o1.y = fmaxf(acc[i][5] + b1.y, 0.f);
            o1.z = fmaxf(acc[i][6] + b1.z, 0.f);
            o1.w = fmaxf(acc[i][7] + b1.w, 0.f);
            ((float4*)P)[(size_t)node * 32 + 2 * tx] = o0;
            ((float4*)P)[(size_t)node * 32 + 2 * tx + 1] = o1;
        }
    }
}

// dots[n] = H[n][:] . Wl  — one wave per node, no atomics
__global__ __launch_bounds__(256) void node_dot(const float* __restrict__ H,
                                                const float* __restrict__ Wl,
                                                float* __restrict__ dots, int N) {
    long long gt = (long long)blockIdx.x * 256 + threadIdx.x;
    int n = (int)(gt >> 6);
    int lane = (int)(gt & 63);
    if (n >= N) return;
    float v = H[(size_t)n * 128 + lane] * Wl[lane] +
              H[(size_t)n * 128 + 64 + lane] * Wl[64 + lane];
#pragma unroll
    for (int off = 32; off > 0; off >>= 1) v += __shfl_down(v, off, 64);
    if (lane == 0) dots[n] = v;
}

// one block per graph: binary-search node range in sorted batch, mean, +bl
__global__ __launch_bounds__(256) void pool_graphs(const float* __restrict__ dots,
                                                   const int* __restrict__ batch, int N,
                                                   const float* __restrict__ bl,
                                                   float* __restrict__ out) {
    __shared__ int bounds[2];
    __shared__ float red[4];
    const int g = blockIdx.x;
    const int t = threadIdx.x;
    if (t < 2) {
        int key = g + t;             // lower_bound(batch, key)
        int lo = 0, hi = N;
        while (lo < hi) {
            int mid = (lo + hi) >> 1;
            if (batch[mid] < key) lo = mid + 1; else hi = mid;
        }
        bounds[t] = lo;
    }
    __syncthreads();
    const int lo = bounds[0], hi = bounds[1];
    float s = 0.f;
    for (int i = lo + t; i < hi; i += 256) s += dots[i];
#pragma unroll
    for (int off = 32; off > 0; off >>= 1) s += __shfl_down(s, off, 64);
    if ((t & 63) == 0) red[t >> 6] = s;
    __syncthreads();
    if (t == 0) {
        float tot = red[0] + red[1] + red[2] + red[3];
        int cnt = hi - lo;
        out[g] = tot / (float)(cnt > 0 ? cnt : 1) + bl[0];
    }
}

extern "C" void kernel_launch(void* const* d_in, const int* in_sizes, int n_in,
                              void* d_out, int out_size, void* d_ws, size_t ws_size,
                              hipStream_t stream) {
    const float* x     = (const float*)d_in[0];
    const int*   eidx  = (const int*)d_in[1];    // int32 (harness converts int64)
    const int*   batch = (const int*)d_in[2];
    const float* Ws    = (const float*)d_in[3];
    const float* bs    = (const float*)d_in[4];
    const float* Wl    = (const float*)d_in[5];
    const float* bl    = (const float*)d_in[6];
    (void)n_in; (void)out_size;

    const int N = in_sizes[0] / D;
    const int E = in_sizes[1] / 2;
    const int* er = eidx;       // sources
    const int* ec = eidx + E;   // targets

    // ---- workspace carve ----
    const size_t bufBytes = (size_t)N * D * sizeof(float);   // 51.2 MB
    const int Npad = (N + 63) & ~63;
    auto al = [](size_t v) { return (v + 255) & ~(size_t)255; };
    char* base = (char*)d_ws;
    size_t off = 0;

    float* wsA = (float*)base;               off = al(bufBytes);
    // zero-block: degi, cursor (contiguous -> one zero kernel)
    int*   degi   = (int*)(base + off);
    int*   cursor = degi + Npad;
    const int zeroInts = 2 * Npad;
    off = al(off + (size_t)zeroInts * sizeof(int));
    float* dinv   = (float*)(base + off);    off = al(off + (size_t)Npad * sizeof(float));
    float* dots   = (float*)(base + off);    off = al(off + (size_t)Npad * sizeof(float));
    int*   rowptr = (int*)(base + off);      off = al(off + (size_t)(Npad + 64) * sizeof(int));
    int*   bsum   = (int*)(base + off);      off = al(off + 256 * sizeof(int));
    int*   srcs   = (int*)(base + off);      off = al(off + (size_t)E * sizeof(int));
    float* vals   = (float*)(base + off);    off = al(off + (size_t)E * sizeof(float));

    const bool twoBuf = ws_size >= off + bufBytes;
    float* wsB = twoBuf ? (float*)(base + off) : (float*)d_in[0];
    float* bufs[2] = { wsA, wsB };

    // ---- CSR build (once; reused by all 4 layers) ----
    zero_i4<<<(zeroInts / 4 + 255) / 256, 256, 0, stream>>>((int4*)degi, zeroInts / 4);
    count_deg<<<(E + 255) / 256, 256, 0, stream>>>(ec, E, degi);
    make_dinv<<<(N + 255) / 256, 256, 0, stream>>>(degi, dinv, N);
    const int NB = (N + 1023) / 1024;
    scan1<<<NB, 256, 0, stream>>>(degi, N, bsum);
    scan2<<<1, 256, 0, stream>>>(bsum, NB);
    scan3<<<NB, 256, 0, stream>>>(degi, bsum, N, E, rowptr);
    fill_edges<<<(E + 255) / 256, 256, 0, stream>>>(er, ec, E, rowptr, cursor, dinv, srcs, vals);

    // ---- 4 layers: pull-aggregate (norm fully folded) -> in-place GEMM ----
    for (int i = 0; i < 4; ++i) {
        float* P = bufs[i & 1];
        const float* H = (i == 0) ? x : bufs[(i - 1) & 1];
        pull_agg<<<(N + 7) / 8, 256, 0, stream>>>(rowptr, srcs, vals, dinv, H, P, N);
        gemm_agg<<<(N + 63) / 64, 256, 0, stream>>>(P, Ws + (size_t)i * D * D,
                                                    bs + (size_t)i * D, N);
    }

    // ---- mean pool + linear head (final features in bufs[1]) ----
    long long tot = (long long)N * 64;
    node_dot<<<(int)((tot + 255) / 256), 256, 0, stream>>>(bufs[1], Wl, dots, N);
    pool_graphs<<<NGRAPH, 256, 0, stream>>>(dots, batch, N, bl, (float*)d_out);
}